// Round 4
// baseline (391.131 us; speedup 1.0000x reference)
//
#include <hip/hip_runtime.h>

// LIF neuron scan: u = u*DECAY + x_t; s = (u - V_TH > 0); u *= (1 - s).
// Memory-bound: 205.5 MB read + 205.5 MB write = 411 MB -> ~65 us floor
// at ~6.3 TB/s achievable.
//
// R1: kernel absent from rocprof top-5 (harness fills at ~126 us dominate);
//     bench dur_us bundles harness restore/poison traffic.
// R3: nt loads/stores: 333.8 -> 325.1 us (-2.6%).
// R4 PROBE: launch the identical kernel TWICE. dur_us - 325.1 = true kernel
//     time (graph-safe, idempotent: second launch recomputes same outputs).
//     delta <= ~80 us => kernel at roofline; ~130 us => 2x headroom to chase.

#define V_TH  1.0f
#define DECAY 0.25f

typedef float v4f __attribute__((ext_vector_type(4)));

__global__ __launch_bounds__(256) void lif_kernel(const v4f* __restrict__ x,
                                                  v4f* __restrict__ out,
                                                  int n4) {
    int i = blockIdx.x * 256 + threadIdx.x;
    const int stride = gridDim.x * 256;

    for (; i < n4; i += stride) {
        // Load all 4 time planes up front (independent loads -> max MLP).
        v4f x0 = __builtin_nontemporal_load(&x[(size_t)0 * n4 + i]);
        v4f x1 = __builtin_nontemporal_load(&x[(size_t)1 * n4 + i]);
        v4f x2 = __builtin_nontemporal_load(&x[(size_t)2 * n4 + i]);
        v4f x3 = __builtin_nontemporal_load(&x[(size_t)3 * n4 + i]);

        v4f u = (v4f)(0.f);
        v4f s0, s1, s2, s3;

        // Step: u = u*DECAY + xt (exact: DECAY is 2^-2); spike; hard reset.
#define LIF_STEP(xt, st)                                                      \
        do {                                                                  \
            u = u * DECAY + (xt);                                             \
            (st).x = (u.x > V_TH) ? 1.f : 0.f;                                \
            (st).y = (u.y > V_TH) ? 1.f : 0.f;                                \
            (st).z = (u.z > V_TH) ? 1.f : 0.f;                                \
            (st).w = (u.w > V_TH) ? 1.f : 0.f;                                \
            u.x = (u.x > V_TH) ? 0.f : u.x;                                   \
            u.y = (u.y > V_TH) ? 0.f : u.y;                                   \
            u.z = (u.z > V_TH) ? 0.f : u.z;                                   \
            u.w = (u.w > V_TH) ? 0.f : u.w;                                   \
        } while (0)

        LIF_STEP(x0, s0);
        LIF_STEP(x1, s1);
        LIF_STEP(x2, s2);
        LIF_STEP(x3, s3);
#undef LIF_STEP

        __builtin_nontemporal_store(s0, &out[(size_t)0 * n4 + i]);
        __builtin_nontemporal_store(s1, &out[(size_t)1 * n4 + i]);
        __builtin_nontemporal_store(s2, &out[(size_t)2 * n4 + i]);
        __builtin_nontemporal_store(s3, &out[(size_t)3 * n4 + i]);
    }
}

extern "C" void kernel_launch(void* const* d_in, const int* in_sizes, int n_in,
                              void* d_out, int out_size, void* d_ws, size_t ws_size,
                              hipStream_t stream) {
    const v4f* x = (const v4f*)d_in[0];
    v4f* out = (v4f*)d_out;

    const int n4 = out_size / 4 / 4;  // 3,211,264
    const int block = 256;
    const int grid = (n4 + block - 1) / block;  // 12,544 blocks

    // PROBE: two identical launches. dur_us(R4) - dur_us(R3) = one kernel's
    // true duration. Idempotent => correctness unchanged.
    lif_kernel<<<grid, block, 0, stream>>>(x, out, n4);
    lif_kernel<<<grid, block, 0, stream>>>(x, out, n4);
}

// Round 5
// 324.281 us; speedup vs baseline: 1.2061x; 1.2061x over previous
//
#include <hip/hip_runtime.h>

// LIF neuron scan: u = u*DECAY + x_t; s = (u - V_TH > 0); u *= (1 - s).
// T=4 sequential steps, fully parallel over 12.8M spatial slots.
//
// ROOFLINE ANALYSIS (R4 double-launch probe):
//   one kernel = 391.1 - 325.1 = 66.0 us for 411 MB (205.5 R + 205.5 W)
//   => 6.23 TB/s = ~96% of the 6.5 TB/s measured achievable ceiling.
//   Every byte touched exactly once; no reuse, fp32 in/out fixed by harness.
//   63 us is the hard floor; kernel is at it. Remaining bench dur_us
//   (~259 us) is harness restore/poison traffic.
//
// Journal: R1 float4 baseline (kernel <=125us); R3 +nt loads/stores (-2.6%
// bench-level); R4 probe measured kernel=66us; R5 revert probe -> final.

#define V_TH  1.0f
#define DECAY 0.25f

typedef float v4f __attribute__((ext_vector_type(4)));

__global__ __launch_bounds__(256) void lif_kernel(const v4f* __restrict__ x,
                                                  v4f* __restrict__ out,
                                                  int n4) {
    int i = blockIdx.x * 256 + threadIdx.x;
    const int stride = gridDim.x * 256;

    for (; i < n4; i += stride) {
        // Load all 4 time planes up front (independent loads -> max MLP).
        // Nontemporal: single-use streaming data, skip LLC retention.
        v4f x0 = __builtin_nontemporal_load(&x[(size_t)0 * n4 + i]);
        v4f x1 = __builtin_nontemporal_load(&x[(size_t)1 * n4 + i]);
        v4f x2 = __builtin_nontemporal_load(&x[(size_t)2 * n4 + i]);
        v4f x3 = __builtin_nontemporal_load(&x[(size_t)3 * n4 + i]);

        v4f u = (v4f)(0.f);
        v4f s0, s1, s2, s3;

        // Step: u = u*DECAY + xt (exact: DECAY=2^-2 => fp32 bit-exact vs ref,
        // absmax stays 0); spike; hard reset.
#define LIF_STEP(xt, st)                                                      \
        do {                                                                  \
            u = u * DECAY + (xt);                                             \
            (st).x = (u.x > V_TH) ? 1.f : 0.f;                                \
            (st).y = (u.y > V_TH) ? 1.f : 0.f;                                \
            (st).z = (u.z > V_TH) ? 1.f : 0.f;                                \
            (st).w = (u.w > V_TH) ? 1.f : 0.f;                                \
            u.x = (u.x > V_TH) ? 0.f : u.x;                                   \
            u.y = (u.y > V_TH) ? 0.f : u.y;                                   \
            u.z = (u.z > V_TH) ? 0.f : u.z;                                   \
            u.w = (u.w > V_TH) ? 0.f : u.w;                                   \
        } while (0)

        LIF_STEP(x0, s0);
        LIF_STEP(x1, s1);
        LIF_STEP(x2, s2);
        LIF_STEP(x3, s3);
#undef LIF_STEP

        __builtin_nontemporal_store(s0, &out[(size_t)0 * n4 + i]);
        __builtin_nontemporal_store(s1, &out[(size_t)1 * n4 + i]);
        __builtin_nontemporal_store(s2, &out[(size_t)2 * n4 + i]);
        __builtin_nontemporal_store(s3, &out[(size_t)3 * n4 + i]);
    }
}

extern "C" void kernel_launch(void* const* d_in, const int* in_sizes, int n_in,
                              void* d_out, int out_size, void* d_ws, size_t ws_size,
                              hipStream_t stream) {
    const v4f* x = (const v4f*)d_in[0];
    v4f* out = (v4f*)d_out;

    const int n4 = out_size / 4 / 4;  // 3,211,264
    const int block = 256;
    const int grid = (n4 + block - 1) / block;  // 12,544 blocks

    lif_kernel<<<grid, block, 0, stream>>>(x, out, n4);
}